// Round 13
// baseline (193.731 us; speedup 1.0000x reference)
//
#include <hip/hip_runtime.h>
#include <math.h>

// VectorQuantizer — bit-exact emulation of the numpy fp32 reference (proven R2-R12):
//   d[n,k] = fl32( fl32(x2[n]+c2[k]) - fl32(2 * fl32(exact_fp64_dot)) ), first argmin.
// R12 (126us kernel) is fp32-VALU-bound: 32 fmaf/dim-step, pure-issue floor ~64us.
// R13 moves the fast scan to matrix cores: bf16 hi/lo split (x=xh+xl, c=ch+cl),
// dot ~= xh*ch + xh*cl + xl*ch on mfma_f32_16x16x32_bf16 (err <= ~3e-6 << THR).
// Exact ranking still by the bit-identical R2 fp64 resolver over the captured
// near-best superset => reference argmin independent of MFMA rounding.
// Layout (HW-verified per guide m89/m91/m92/m120): A,B frags row-major 8 contig
// K-elems per lane (lane&15=m/n, quad=K-octet) -> D = A*B^T, D: col=lane&15=n,
// row=quad*4+reg=m. Block = 64 rows x 512 codes, 8 waves; wave owns 64 codes
// with B-frags RESIDENT in 64 VGPRs (one-time load from pre-split cbh/cbl ws).

#define N_CODES   512
#define CODE_DIM  64
#define CH_STRIDE 4096                       // floats between channels
#define B_STRIDE  (CODE_DIM * CH_STRIDE)     // floats between batches
#define XSP       65                         // fp32 xs pitch (floats)  -> conflict-free
#define XHP       72                         // bf16 xh/xl pitch (shorts) -> 2-way free
#define THR       1.5e-4f                    // >= ~7x (fast-vs-exact bound ~2.2e-5)

typedef __attribute__((ext_vector_type(8))) short bf16x8;   // 8 bf16 = 4 VGPRs
typedef __attribute__((ext_vector_type(4))) float f32x4;

__device__ __forceinline__ unsigned short f2bf(float f) {   // fp32 -> bf16 (RNE)
    unsigned u = __float_as_uint(f);
    unsigned r = u + 0x7FFFu + ((u >> 16) & 1u);
    return (unsigned short)(r >> 16);
}
__device__ __forceinline__ float bf2f(unsigned short h) {
    return __uint_as_float(((unsigned)h) << 16);
}

// ---------------- setup: c2 (numpy pairwise) + bf16 hi/lo codebook ----------
__device__ __forceinline__ float np_pairwise_sum64(const float* a) {
    float r[8];
#pragma unroll
    for (int j = 0; j < 8; ++j) r[j] = a[j];
#pragma unroll
    for (int i = 8; i < 64; i += 8) {
#pragma unroll
        for (int j = 0; j < 8; ++j) r[j] = __fadd_rn(r[j], a[i + j]);
    }
    return __fadd_rn(__fadd_rn(__fadd_rn(r[0], r[1]), __fadd_rn(r[2], r[3])),
                     __fadd_rn(__fadd_rn(r[4], r[5]), __fadd_rn(r[6], r[7])));
}

__global__ void vq_setup_kernel(const float* __restrict__ cb, float* __restrict__ c2,
                                unsigned short* __restrict__ cbh,
                                unsigned short* __restrict__ cbl, int build) {
    const int t = blockIdx.x * blockDim.x + threadIdx.x;   // 64 x 512 = 32768
    if (build && t < N_CODES * CODE_DIM) {
        const float c = cb[t];
        const unsigned short h = f2bf(c);
        cbh[t] = h;
        cbl[t] = f2bf(__fsub_rn(c, bf2f(h)));
    }
    if (t < N_CODES) {
        const float* row = cb + t * CODE_DIM;
        float sq[CODE_DIM];
#pragma unroll
        for (int j = 0; j < CODE_DIM; ++j) sq[j] = __fmul_rn(row[j], row[j]);
        c2[t] = np_pairwise_sum64(sq);
    }
}

// Rare-path exact resolver — bit-identical R2 arithmetic. __noinline__, touches
// only LDS (xs, x2e, res) and global (cb, c2): caller register arrays stay put.
__device__ __noinline__ void resolve_cell(const float* __restrict__ cb,
                                          const float* __restrict__ c2g,
                                          const float* xs, const float* x2e,
                                          unsigned long long* s_res,
                                          int row, int k) {
    const float* crow = cb + (size_t)k * CODE_DIM;
    const float* xr   = xs + row * XSP;
    double b0 = 0.0, b1 = 0.0, b2 = 0.0, b3 = 0.0;
#pragma unroll
    for (int c = 0; c < CODE_DIM; c += 4) {
        b0 = fma((double)crow[c + 0], (double)xr[c + 0], b0);
        b1 = fma((double)crow[c + 1], (double)xr[c + 1], b1);
        b2 = fma((double)crow[c + 2], (double)xr[c + 2], b2);
        b3 = fma((double)crow[c + 3], (double)xr[c + 3], b3);
    }
    const double dot64 = (b0 + b1) + (b2 + b3);
    const float  ein   = (float)dot64;
    const float  tmp   = __fadd_rn(x2e[row], c2g[k]);
    const float  dk    = __fsub_rn(tmp, __fmul_rn(2.0f, ein));
    const unsigned u     = __float_as_uint(dk);
    const unsigned key32 = (u & 0x80000000u) ? ~u : (u | 0x80000000u);
    atomicMin(&s_res[row], ((unsigned long long)key32 << 32) | (unsigned)k);
}

// ---------------- main: MFMA fast scan + exact resolve ----------------------
__global__ __launch_bounds__(512)
void vq_mfma_kernel(const float* __restrict__ in,
                    const float* __restrict__ cb,
                    const float* __restrict__ c2g,
                    const unsigned short* __restrict__ cbh,
                    const unsigned short* __restrict__ cbl,
                    float* __restrict__ out) {
    __shared__ float xs[64 * XSP];            // fp32 x rows (resolver/x2e), 16.6KB
    __shared__ short xh[64 * XHP];            // bf16 hi, 9.2KB
    __shared__ short xl[64 * XHP];            // bf16 lo, 9.2KB
    __shared__ float s_wm[8][64];             // per-wave per-row fast min
    __shared__ float s_bmin[64];
    __shared__ float s_x2e[64];               // numpy-exact x2 per row
    __shared__ unsigned long long s_res[64];  // packed (dk-key, k)

    const int tid  = threadIdx.x;
    const int lane = tid & 63;
    const int wid  = tid >> 6;                // 0..7 -> 64-code range
    const int gw   = blockIdx.x;              // (b,h) group
    const float* src = in + (size_t)(gw >> 6) * B_STRIDE + (size_t)(gw & 63) * 64;

    // --- stage fp32 x rows (coalesced: consecutive tid -> consecutive w) -----
#pragma unroll
    for (int i = 0; i < 8; ++i) {
        const int idx = (i << 9) | tid;        // 0..4095 = c*64 + w
        const int c = idx >> 6, w = idx & 63;
        xs[w * XSP + c] = src[(size_t)c * CH_STRIDE + w];
    }
    if (tid < 64) s_res[tid] = ~0ull;
    __syncthreads();

    // --- bf16 hi/lo split into xh/xl (packed u32 pair writes) ----------------
#pragma unroll
    for (int i = 0; i < 4; ++i) {
        const int idx = (i << 9) | tid;        // pair index 0..2047
        const int row = idx >> 5, dp = idx & 31;
        const float f0 = xs[row * XSP + 2 * dp];
        const float f1 = xs[row * XSP + 2 * dp + 1];
        const unsigned short h0 = f2bf(f0), h1 = f2bf(f1);
        const unsigned short l0 = f2bf(__fsub_rn(f0, bf2f(h0)));
        const unsigned short l1 = f2bf(__fsub_rn(f1, bf2f(h1)));
        ((unsigned*)xh)[row * (XHP / 2) + dp] = (unsigned)h0 | ((unsigned)h1 << 16);
        ((unsigned*)xl)[row * (XHP / 2) + dp] = (unsigned)l0 | ((unsigned)l1 << 16);
    }
    // --- numpy-exact x2 per row (R5-proven rolling order; xs is ready) -------
    if (tid < 64) {
        const float* xr = xs + tid * XSP;
        float r8[8];
#pragma unroll
        for (int j = 0; j < 8; ++j) r8[j] = __fmul_rn(xr[j], xr[j]);
#pragma unroll
        for (int i = 8; i < 64; i += 8) {
#pragma unroll
            for (int j = 0; j < 8; ++j)
                r8[j] = __fadd_rn(r8[j], __fmul_rn(xr[i + j], xr[i + j]));
        }
        s_x2e[tid] = __fadd_rn(
            __fadd_rn(__fadd_rn(r8[0], r8[1]), __fadd_rn(r8[2], r8[3])),
            __fadd_rn(__fadd_rn(r8[4], r8[5]), __fadd_rn(r8[6], r8[7])));
    }

    // --- resident B-frags: this wave's 64 codes (4 tiles of 16) --------------
    const int code0 = wid * 64;
    const int n     = lane & 15;              // code-in-tile / A row-in-group
    const int quad  = lane >> 4;              // K-octet selector
    bf16x8 Bh[4][2], Bl[4][2];
#pragma unroll
    for (int t = 0; t < 4; ++t) {
        const unsigned short* ph = cbh + (size_t)(code0 + t * 16 + n) * CODE_DIM + quad * 8;
        const unsigned short* pl = cbl + (size_t)(code0 + t * 16 + n) * CODE_DIM + quad * 8;
        Bh[t][0] = *(const bf16x8*)ph;
        Bh[t][1] = *(const bf16x8*)(ph + 32);
        Bl[t][0] = *(const bf16x8*)pl;
        Bl[t][1] = *(const bf16x8*)(pl + 32);
    }
    float c2v[4];
#pragma unroll
    for (int t = 0; t < 4; ++t) c2v[t] = c2g[code0 + t * 16 + n];
    __syncthreads();

    // --- 4 row-groups of 16 rows: 6 MFMA per 16x16 tile (hh,hl,lh) -----------
#pragma unroll 1
    for (int rg = 0; rg < 4; ++rg) {
        const int rb = rg * 16;
        const short* pah = xh + (rb + n) * XHP + quad * 8;   // khalf0 octet
        const short* pal = xl + (rb + n) * XHP + quad * 8;
        const bf16x8 Ah0 = *(const bf16x8*)pah;
        const bf16x8 Ah1 = *(const bf16x8*)(pah + 32);       // khalf1 octet
        const bf16x8 Al0 = *(const bf16x8*)pal;
        const bf16x8 Al1 = *(const bf16x8*)(pal + 32);

        float ek[4][4];
#pragma unroll
        for (int t = 0; t < 4; ++t) {
            f32x4 acc = {0.f, 0.f, 0.f, 0.f};
            acc = __builtin_amdgcn_mfma_f32_16x16x32_bf16(Ah0, Bh[t][0], acc, 0, 0, 0);
            acc = __builtin_amdgcn_mfma_f32_16x16x32_bf16(Ah1, Bh[t][1], acc, 0, 0, 0);
            acc = __builtin_amdgcn_mfma_f32_16x16x32_bf16(Ah0, Bl[t][0], acc, 0, 0, 0);
            acc = __builtin_amdgcn_mfma_f32_16x16x32_bf16(Ah1, Bl[t][1], acc, 0, 0, 0);
            acc = __builtin_amdgcn_mfma_f32_16x16x32_bf16(Al0, Bh[t][0], acc, 0, 0, 0);
            acc = __builtin_amdgcn_mfma_f32_16x16x32_bf16(Al1, Bh[t][1], acc, 0, 0, 0);
#pragma unroll
            for (int r = 0; r < 4; ++r)
                ek[t][r] = __fmaf_rn(-2.0f, acc[r], c2v[t]);  // x2 shift invariant
        }

        // per-row fast min: over own 4 tiles, then across the 16 n-lanes
        float m0[4];
#pragma unroll
        for (int r = 0; r < 4; ++r)
            m0[r] = fminf(fminf(ek[0][r], ek[1][r]), fminf(ek[2][r], ek[3][r]));
#pragma unroll
        for (int s = 1; s < 16; s <<= 1) {
#pragma unroll
            for (int r = 0; r < 4; ++r) m0[r] = fminf(m0[r], __shfl_xor(m0[r], s, 64));
        }
        if (n == 0) {
#pragma unroll
            for (int r = 0; r < 4; ++r) s_wm[wid][rb + quad * 4 + r] = m0[r];
        }
        __syncthreads();
        if (tid < 16) {
            float bm = s_wm[0][rb + tid];
#pragma unroll
            for (int w2 = 1; w2 < 8; ++w2) bm = fminf(bm, s_wm[w2][rb + tid]);
            s_bmin[rb + tid] = bm;
        }
        __syncthreads();

        // filter (compile-time ek indices) + rare exact resolve
#pragma unroll
        for (int t = 0; t < 4; ++t) {
#pragma unroll
            for (int r = 0; r < 4; ++r) {
                const int row = rb + quad * 4 + r;             // D row = m
                if (ek[t][r] <= s_bmin[row] + THR)
                    resolve_cell(cb, c2g, xs, s_x2e, s_res, row, code0 + t * 16 + n);
            }
        }
        __syncthreads();
    }

    // --- output: wave wid writes rows wid*8..+7 (coalesced 256B each) --------
    const size_t n0 = (size_t)gw * 64;
#pragma unroll 1
    for (int rr = 0; rr < 8; ++rr) {
        const int row = wid * 8 + rr;
        const int bi  = (int)(s_res[row] & 0xFFFFFFFFull);
        out[(n0 + row) * CODE_DIM + lane] = cb[(size_t)bi * CODE_DIM + lane];
    }
}

// ---------------- fallback (R9-style, proven) if ws too small ---------------
__device__ __forceinline__ float exact_dk_fb(const float* __restrict__ cb,
                                             const float* __restrict__ c2,
                                             const float (&x)[CODE_DIM], float x2, int k) {
    const float* crow = cb + (size_t)k * CODE_DIM;
    double a0 = 0.0, a1 = 0.0, a2 = 0.0, a3 = 0.0;
#pragma unroll
    for (int j = 0; j < CODE_DIM; j += 4) {
        a0 = fma((double)crow[j + 0], (double)x[j + 0], a0);
        a1 = fma((double)crow[j + 1], (double)x[j + 1], a1);
        a2 = fma((double)crow[j + 2], (double)x[j + 2], a2);
        a3 = fma((double)crow[j + 3], (double)x[j + 3], a3);
    }
    const double dot = (a0 + a1) + (a2 + a3);
    const float  ein = (float)dot;
    return __fsub_rn(__fadd_rn(x2, c2[k]), __fmul_rn(2.0f, ein));
}

__global__ __launch_bounds__(512, 2)
void vq_fallback_kernel(const float* __restrict__ in, const float* __restrict__ cb,
                        const float* __restrict__ c2, float* __restrict__ out) {
    __shared__ float s_rb[8][64];
    __shared__ int   s_ri[8][64];
    const int tid = threadIdx.x, lane = tid & 63, wid = tid >> 6;
    const int gw = blockIdx.x, b = gw >> 6, h = gw & 63;
    const float* xin = in + (size_t)b * B_STRIDE + (size_t)h * 64 + lane;
    float x[CODE_DIM];
#pragma unroll
    for (int c = 0; c < CODE_DIM; ++c) x[c] = xin[(size_t)c * CH_STRIDE];
    float r[8];
#pragma unroll
    for (int j = 0; j < 8; ++j) r[j] = __fmul_rn(x[j], x[j]);
#pragma unroll
    for (int i = 8; i < 64; i += 8)
#pragma unroll
        for (int j = 0; j < 8; ++j) r[j] = __fadd_rn(r[j], __fmul_rn(x[i + j], x[i + j]));
    const float x2 = __fadd_rn(__fadd_rn(__fadd_rn(r[0], r[1]), __fadd_rn(r[2], r[3])),
                               __fadd_rn(__fadd_rn(r[4], r[5]), __fadd_rn(r[6], r[7])));
    const int k0 = __builtin_amdgcn_readfirstlane(wid) * 64;
    float ex_best = INFINITY; int bi = k0;
#pragma unroll 1
    for (int kk = 0; kk < 64; ++kk) {
        const float dk = exact_dk_fb(cb, c2, x, x2, k0 + kk);
        if (dk < ex_best) { ex_best = dk; bi = k0 + kk; }
    }
    s_rb[wid][lane] = ex_best; s_ri[wid][lane] = bi;
    __syncthreads();
    float fb2 = s_rb[0][lane]; int fi = s_ri[0][lane];
#pragma unroll
    for (int w = 1; w < 8; ++w) {
        if (s_rb[w][lane] < fb2) { fb2 = s_rb[w][lane]; fi = s_ri[w][lane]; }
    }
    const size_t n0 = (size_t)gw * 64;
#pragma unroll 1
    for (int rr = 0; rr < 8; ++rr) {
        const int row = wid * 8 + rr;
        const int idxr = __shfl(fi, row, 64);
        out[(n0 + row) * CODE_DIM + lane] = cb[(size_t)idxr * CODE_DIM + lane];
    }
}

extern "C" void kernel_launch(void* const* d_in, const int* in_sizes, int n_in,
                              void* d_out, int out_size, void* d_ws, size_t ws_size,
                              hipStream_t stream) {
    const float* in  = (const float*)d_in[0];   // (16,64,64,64) fp32
    const float* cb  = (const float*)d_in[1];   // (512,64) fp32
    float*       out = (float*)d_out;           // (16,64,64,64) fp32

    float*          c2  = (float*)d_ws;                              // 2 KB
    unsigned short* cbh = (unsigned short*)((char*)d_ws + 2048);     // 64 KB
    unsigned short* cbl = cbh + N_CODES * CODE_DIM;                  // 64 KB
    const bool hasW = ws_size >=
        (size_t)(2048 + 2 * N_CODES * CODE_DIM * sizeof(unsigned short));  // 130 KB (same as R11/R12 -> available)

    vq_setup_kernel<<<dim3(64), dim3(512), 0, stream>>>(cb, c2, cbh, cbl, hasW ? 1 : 0);
    if (hasW) {
        vq_mfma_kernel<<<dim3(1024), dim3(512), 0, stream>>>(in, cb, c2, cbh, cbl, out);
    } else {
        vq_fallback_kernel<<<dim3(1024), dim3(512), 0, stream>>>(in, cb, c2, out);
    }
}